// Round 3
// baseline (32.771 us; speedup 1.0000x reference)
//
#include <hip/hip_runtime.h>
#include <hip/hip_bf16.h>

#define BB   8
#define CC   128
#define TLEN 8192
#define TBLK 32
#define NTBLK (TLEN / TBLK)          // 256 t-tiles
#define NBLOCKS (NTBLK * BB)         // 2048 blocks = 8 per CU, all co-resident
// d_ws layout: [0 .. 8KB)  : 2048 f32 loss partials
//              [8KB .. 40KB): W as bf16 in MFMA A-frag order
#define WS_W_OFF 8192

typedef __attribute__((ext_vector_type(8))) short short8;
typedef __attribute__((ext_vector_type(4))) float f32x4;

__device__ __forceinline__ short f2bf(float f) {
    union { float f; unsigned u; } v; v.f = f;
    return (short)((v.u + 0x7FFFu + ((v.u >> 16) & 1u)) >> 16);
}
__device__ __forceinline__ float bf2f(unsigned short h) {
    union { unsigned u; float f; } v; v.u = ((unsigned)h) << 16;
    return v.f;
}

// ---- prep: W f32 [128][128] -> bf16 fragments in exact A-operand order ----
// frag element (dtile 0..7, ks 0..3, lane 0..63, e 0..7):
//   row = dtile*16 + (lane&15), col = ks*32 + (lane>>4)*8 + e
__global__ void prep_w(const float* __restrict__ W, short* __restrict__ wsW) {
    const int gid   = blockIdx.x * 256 + threadIdx.x;   // 0..2047
    const int lane  = gid & 63;
    const int ksdt  = gid >> 6;                          // 0..31
    const int dtile = ksdt >> 2;
    const int ks    = ksdt & 3;
    const int row   = dtile * 16 + (lane & 15);
    const int col0  = ks * 32 + (lane >> 4) * 8;
    short8 a;
    #pragma unroll
    for (int e = 0; e < 8; ++e) a[e] = f2bf(W[row * CC + col0 + e]);
    reinterpret_cast<short8*>(wsW)[gid] = a;
}

__global__ __launch_bounds__(256, 8)
void cfm_main(const float* __restrict__ x1, const float* __restrict__ tsm,
              const float* __restrict__ z, const short* __restrict__ wsW,
              const float* __restrict__ blin, const int* __restrict__ xlens,
              const int* __restrict__ plens, float* __restrict__ out,
              float* __restrict__ wsPart)
{
    __shared__ short xt[TBLK][136];   // x1 tile bf16, [t][c], 272B rows
    __shared__ short zt[TBLK][136];   // z  tile bf16, [t][c]
    __shared__ float red[4];

    const int b    = blockIdx.y;
    const int t0   = blockIdx.x * TBLK;
    const int tid  = threadIdx.x;
    const int lane = tid & 63;
    const int wid  = tid >> 6;
    const int r15  = lane & 15;
    const int q4   = lane >> 4;

    const float ts  = tsm[b];
    const int   pl  = plens[b];
    const int   xl  = xlens[b];
    const float oms = 0.999999f;           // 1 - sigma
    const float cz  = 1.0f - oms * ts;
    const float cx  = ts;

    const short8* wf = reinterpret_cast<const short8*>(wsW);

    // ---- phase 1: issue ALL global loads up front (8 float4 in flight) ----
    const int tcol = (tid & 7) * 4;
    const int crow = tid >> 3;             // 0..31
    const size_t gbase = (size_t)b * CC * TLEN + (size_t)t0 + tcol;

    float4 xv[4], zv[4];
    #pragma unroll
    for (int p = 0; p < 4; ++p)
        xv[p] = *reinterpret_cast<const float4*>(x1 + gbase + (size_t)(p * 32 + crow) * TLEN);
    #pragma unroll
    for (int p = 0; p < 4; ++p)
        zv[p] = *reinterpret_cast<const float4*>(z + gbase + (size_t)(p * 32 + crow) * TLEN);

    // A-frags for pass 0 (d-tile wid*2+0): issue early, L2-hot, overlaps staging
    short8 af0[4];
    #pragma unroll
    for (int ks = 0; ks < 4; ++ks)
        af0[ks] = wf[((wid * 2 + 0) * 4 + ks) * 64 + lane];

    // ---- phase 2: convert + transposed LDS stage ----
    #pragma unroll
    for (int p = 0; p < 4; ++p) {
        const int c = p * 32 + crow;
        const float* xs = reinterpret_cast<const float*>(&xv[p]);
        const float* zs = reinterpret_cast<const float*>(&zv[p]);
        #pragma unroll
        for (int j = 0; j < 4; ++j) {
            xt[tcol + j][c] = f2bf(xs[j]);
            zt[tcol + j][c] = f2bf(zs[j]);
        }
    }
    __syncthreads();

    float lsum = 0.0f;

    // ================= pass 0: d in [wid*32, wid*32+16) =================
    {
        // prefetch A-frags for pass 1 while pass-0 MFMAs run
        short8 af1[4];
        #pragma unroll
        for (int ks = 0; ks < 4; ++ks)
            af1[ks] = wf[((wid * 2 + 1) * 4 + ks) * 64 + lane];

        f32x4 ax[2], az[2];
        #pragma unroll
        for (int tt = 0; tt < 2; ++tt) { ax[tt] = (f32x4){0,0,0,0}; az[tt] = (f32x4){0,0,0,0}; }

        #pragma unroll
        for (int ks = 0; ks < 4; ++ks) {
            #pragma unroll
            for (int tt = 0; tt < 2; ++tt) {
                const short8 xf = *reinterpret_cast<const short8*>(&xt[tt * 16 + r15][ks * 32 + q4 * 8]);
                const short8 zf = *reinterpret_cast<const short8*>(&zt[tt * 16 + r15][ks * 32 + q4 * 8]);
                ax[tt] = __builtin_amdgcn_mfma_f32_16x16x32_bf16(af0[ks], xf, ax[tt], 0, 0, 0);
                az[tt] = __builtin_amdgcn_mfma_f32_16x16x32_bf16(af0[ks], zf, az[tt], 0, 0, 0);
            }
        }

        // epilogue pass 0
        #pragma unroll
        for (int tt = 0; tt < 2; ++tt) {
            const int tl = tt * 16 + r15;
            const int t  = t0 + tl;
            const bool pm = (t >= pl);
            const bool lm = pm & (t < xl);
            #pragma unroll
            for (int rr = 0; rr < 4; ++rr) {
                const int d = wid * 32 + q4 * 4 + rr;
                const float bl = blin[d];
                const float zf = bf2f((unsigned short)zt[tl][d]);
                const float xf = bf2f((unsigned short)xt[tl][d]);
                const float w  = oms * zf;
                const float s  = cx * ax[tt][rr] + cz * az[tt][rr];
                const float ov = (pm ? s : 0.0f) + bl;
                out[1 + (size_t)(b * CC + d) * TLEN + t] = ov + w;
                if (lm) { const float df = ov - (xf - w); lsum += df * df; }
            }
        }

        // ================= pass 1: d in [wid*32+16, wid*32+32) =================
        f32x4 bx[2], bz[2];
        #pragma unroll
        for (int tt = 0; tt < 2; ++tt) { bx[tt] = (f32x4){0,0,0,0}; bz[tt] = (f32x4){0,0,0,0}; }

        #pragma unroll
        for (int ks = 0; ks < 4; ++ks) {
            #pragma unroll
            for (int tt = 0; tt < 2; ++tt) {
                const short8 xf = *reinterpret_cast<const short8*>(&xt[tt * 16 + r15][ks * 32 + q4 * 8]);
                const short8 zf = *reinterpret_cast<const short8*>(&zt[tt * 16 + r15][ks * 32 + q4 * 8]);
                bx[tt] = __builtin_amdgcn_mfma_f32_16x16x32_bf16(af1[ks], xf, bx[tt], 0, 0, 0);
                bz[tt] = __builtin_amdgcn_mfma_f32_16x16x32_bf16(af1[ks], zf, bz[tt], 0, 0, 0);
            }
        }

        #pragma unroll
        for (int tt = 0; tt < 2; ++tt) {
            const int tl = tt * 16 + r15;
            const int t  = t0 + tl;
            const bool pm = (t >= pl);
            const bool lm = pm & (t < xl);
            #pragma unroll
            for (int rr = 0; rr < 4; ++rr) {
                const int d = wid * 32 + 16 + q4 * 4 + rr;
                const float bl = blin[d];
                const float zf = bf2f((unsigned short)zt[tl][d]);
                const float xf = bf2f((unsigned short)xt[tl][d]);
                const float w  = oms * zf;
                const float s  = cx * bx[tt][rr] + cz * bz[tt][rr];
                const float ov = (pm ? s : 0.0f) + bl;
                out[1 + (size_t)(b * CC + d) * TLEN + t] = ov + w;
                if (lm) { const float df = ov - (xf - w); lsum += df * df; }
            }
        }
    }

    // ---- per-wave shuffle reduce -> per-block partial (scaled) ----
    #pragma unroll
    for (int off = 32; off >= 1; off >>= 1) lsum += __shfl_down(lsum, off);
    if (lane == 0) red[wid] = lsum;
    __syncthreads();
    if (tid == 0) {
        const float scale = 1.0f / (1024.0f * (float)(xl - pl));  // 1/(B*C*(xl-pl))
        wsPart[blockIdx.y * gridDim.x + blockIdx.x] =
            (red[0] + red[1] + red[2] + red[3]) * scale;
    }
}

// ---- final: sum 2048 partials -> out[0] ----
__global__ void final_red(const float* __restrict__ wsPart, float* __restrict__ out) {
    __shared__ float red[4];
    const int tid = threadIdx.x;
    float s = 0.0f;
    #pragma unroll
    for (int i = 0; i < NBLOCKS / 256; ++i) s += wsPart[tid + i * 256];
    #pragma unroll
    for (int off = 32; off >= 1; off >>= 1) s += __shfl_down(s, off);
    if ((tid & 63) == 0) red[tid >> 6] = s;
    __syncthreads();
    if (tid == 0) out[0] = red[0] + red[1] + red[2] + red[3];
}

extern "C" void kernel_launch(void* const* d_in, const int* in_sizes, int n_in,
                              void* d_out, int out_size, void* d_ws, size_t ws_size,
                              hipStream_t stream) {
    const float* x1    = (const float*)d_in[0];
    // d_in[1] = mu (unused), d_in[2] = style (unused)
    const float* tsm   = (const float*)d_in[3];
    const float* z     = (const float*)d_in[4];
    const float* W     = (const float*)d_in[5];
    const float* blin  = (const float*)d_in[6];
    const int*   xlens = (const int*)d_in[7];
    const int*   plens = (const int*)d_in[8];
    float* out = (float*)d_out;

    float* wsPart = (float*)d_ws;
    short* wsW    = (short*)((char*)d_ws + WS_W_OFF);

    prep_w<<<8, 256, 0, stream>>>(W, wsW);
    dim3 grid(NTBLK, BB);
    cfm_main<<<grid, 256, 0, stream>>>(x1, tsm, z, wsW, blin, xlens, plens, out, wsPart);
    final_red<<<1, 256, 0, stream>>>(wsPart, out);
}